// Round 1
// baseline (457.928 us; speedup 1.0000x reference)
//
#include <hip/hip_runtime.h>

#define C_DIM 384
#define S_DIM 196
#define CS_   (C_DIM * S_DIM)      // 75264 elements per (tb) slab
#define BCS   (32 * CS_)           // 2408448 elements per t-slab (B*C*S)
#define NELEM (128 * CS_)          // 9633792 total per tensor

// ---------------------------------------------------------------------------
// GEMM + BN:  Y[tb, o, s] = BN( sum_c W[o,c] * X[tb, c, s]  (+ bias[o]) )
// Column index m = tb*196 + s  (m in [0, 25088), exactly 196 tiles of 128)
// 128x128 block tile, BK=8, 8x8 per-thread tile, 256 threads.
// ---------------------------------------------------------------------------
template<bool HAS_BIAS>
__global__ __launch_bounds__(256)
void gemm_bn(const float* __restrict__ X, const float* __restrict__ W,
             const float* __restrict__ gamma, const float* __restrict__ beta,
             const float* __restrict__ mean,  const float* __restrict__ var,
             const float* __restrict__ bias,  float* __restrict__ Y)
{
    __shared__ float As[8][128];   // [k][o]
    __shared__ float Bs[8][128];   // [k][m]

    const int t  = threadIdx.x;
    const int m0 = blockIdx.x * 128;   // 196 tiles
    const int o0 = blockIdx.y * 128;   // 3 tiles

    // A staging: thread loads float4 of W[o0 + t/2, k0 + (t&1)*4 ..]
    const int a_row = t >> 1;
    const int a_col = (t & 1) << 2;
    const float* Ap = W + (o0 + a_row) * C_DIM + a_col;

    // B staging: thread loads float4 of X'[k0 + t/32, m0 + (t&31)*4 ..]
    // 4-column chunk never crosses a tb boundary (196 % 4 == 0).
    const int b_row = t >> 5;
    const int b_ch  = (t & 31) << 2;
    const int bcol  = m0 + b_ch;
    const int btb   = bcol / S_DIM;
    const int bs    = bcol - btb * S_DIM;
    const float* Bp = X + btb * CS_ + b_row * S_DIM + bs;

    const int tx = t & 15, ty = t >> 4;

    float acc[8][8];
    #pragma unroll
    for (int i = 0; i < 8; ++i)
        #pragma unroll
        for (int j = 0; j < 8; ++j) acc[i][j] = 0.0f;

    float4 aReg = *(const float4*)Ap;
    float4 bReg = *(const float4*)Bp;

    for (int kt = 0; kt < 48; ++kt) {
        As[a_col + 0][a_row] = aReg.x;
        As[a_col + 1][a_row] = aReg.y;
        As[a_col + 2][a_row] = aReg.z;
        As[a_col + 3][a_row] = aReg.w;
        *(float4*)&Bs[b_row][b_ch] = bReg;
        __syncthreads();

        if (kt < 47) {  // prefetch next K-slab while computing this one
            aReg = *(const float4*)(Ap + (kt + 1) * 8);
            bReg = *(const float4*)(Bp + (kt + 1) * 8 * S_DIM);
        }

        #pragma unroll
        for (int k = 0; k < 8; ++k) {
            float4 a0 = *(const float4*)&As[k][ty * 4];
            float4 a1 = *(const float4*)&As[k][64 + ty * 4];
            float4 b0 = *(const float4*)&Bs[k][tx * 4];
            float4 b1 = *(const float4*)&Bs[k][64 + tx * 4];
            float av[8] = {a0.x, a0.y, a0.z, a0.w, a1.x, a1.y, a1.z, a1.w};
            float bv[8] = {b0.x, b0.y, b0.z, b0.w, b1.x, b1.y, b1.z, b1.w};
            #pragma unroll
            for (int i = 0; i < 8; ++i)
                #pragma unroll
                for (int j = 0; j < 8; ++j)
                    acc[i][j] += av[i] * bv[j];
        }
        __syncthreads();
    }

    // Epilogue: BN (mirror reference rounding: (acc+bias)*inv + (beta-mean*inv))
    #pragma unroll
    for (int ri = 0; ri < 2; ++ri) {
        #pragma unroll
        for (int r = 0; r < 4; ++r) {
            const int i = ri * 4 + r;
            const int o = o0 + ri * 64 + ty * 4 + r;
            const float inv = gamma[o] / sqrtf(var[o] + 1e-5f);
            const float sh  = beta[o] - mean[o] * inv;
            const float bv  = HAS_BIAS ? bias[o] : 0.0f;
            #pragma unroll
            for (int ci = 0; ci < 2; ++ci) {
                const int col = m0 + ci * 64 + tx * 4;
                const int tb  = col / S_DIM;
                const int s2  = col - tb * S_DIM;
                float4 v;
                v.x = (acc[i][ci * 4 + 0] + bv) * inv + sh;
                v.y = (acc[i][ci * 4 + 1] + bv) * inv + sh;
                v.z = (acc[i][ci * 4 + 2] + bv) * inv + sh;
                v.w = (acc[i][ci * 4 + 3] + bv) * inv + sh;
                *(float4*)(Y + tb * CS_ + o * S_DIM + s2) = v;
            }
        }
    }
}

// ---------------------------------------------------------------------------
// LIF over t for q and k conv outputs; pack 8 spike bits per (b,c,s) element.
// bits 0..3 = q spikes t=0..3, bits 4..7 = k spikes.
// h = v + (x - v)*0.5 ; spike = (h >= 1.0) ; v = spike ? 0 : h
// ---------------------------------------------------------------------------
__global__ __launch_bounds__(256)
void lif_spike_pack(const float* __restrict__ wsq, const float* __restrict__ wsk,
                    unsigned char* __restrict__ spk)
{
    const int i = blockIdx.x * 256 + threadIdx.x;   // over B*C*S
    if (i >= BCS) return;
    float vq = 0.0f, vk = 0.0f;
    int bits = 0;
    #pragma unroll
    for (int t = 0; t < 4; ++t) {
        const float xq = wsq[t * BCS + i];
        const float hq = vq + (xq - vq) * 0.5f;
        const int sq = (hq >= 1.0f);
        vq = sq ? 0.0f : hq;
        bits |= sq << t;

        const float xk = wsk[t * BCS + i];
        const float hk = vk + (xk - vk) * 0.5f;
        const int sk = (hk >= 1.0f);
        vk = sk ? 0.0f : hk;
        bits |= sk << (4 + t);
    }
    spk[i] = (unsigned char)bits;
}

// ---------------------------------------------------------------------------
// Per (b, head, s): qs[t] = sum over 48 channels of q spikes; attn = LIF(qs,
// v_th=0.5) — exact dyadic arithmetic; y = attn * k_spike, written as {0,1} f32.
// ---------------------------------------------------------------------------
__global__ __launch_bounds__(256)
void attn_gate(const unsigned char* __restrict__ spk, float* __restrict__ y)
{
    const int b    = blockIdx.x >> 3;
    const int head = blockIdx.x & 7;
    const int s    = threadIdx.x;
    if (s >= S_DIM) return;

    const unsigned char* sp = spk + b * CS_ + head * 48 * S_DIM + s;
    int qs[4] = {0, 0, 0, 0};
    unsigned long long kb[4] = {0ull, 0ull, 0ull, 0ull};

    for (int c = 0; c < 48; ++c) {
        const int v = sp[c * S_DIM];
        #pragma unroll
        for (int t = 0; t < 4; ++t) {
            qs[t] += (v >> t) & 1;
            kb[t] |= (unsigned long long)((v >> (4 + t)) & 1) << c;
        }
    }

    float va = 0.0f;
    int attn[4];
    #pragma unroll
    for (int t = 0; t < 4; ++t) {
        const float h = va + ((float)qs[t] - va) * 0.5f;
        const int a = (h >= 0.5f);
        va = a ? 0.0f : h;
        attn[t] = a;
    }

    float* yp = y + b * CS_ + head * 48 * S_DIM + s;
    for (int c = 0; c < 48; ++c) {
        #pragma unroll
        for (int t = 0; t < 4; ++t) {
            yp[t * BCS + c * S_DIM] =
                (attn[t] && ((kb[t] >> c) & 1)) ? 1.0f : 0.0f;
        }
    }
}

// ---------------------------------------------------------------------------
// Final LIF over t on proj output -> spikes to d_out.
// ---------------------------------------------------------------------------
__global__ __launch_bounds__(256)
void lif_out(const float* __restrict__ z, float* __restrict__ out)
{
    const int i = blockIdx.x * 256 + threadIdx.x;
    if (i >= BCS) return;
    float v = 0.0f;
    #pragma unroll
    for (int t = 0; t < 4; ++t) {
        const float x = z[t * BCS + i];
        const float h = v + (x - v) * 0.5f;
        const int sp = (h >= 1.0f);
        v = sp ? 0.0f : h;
        out[t * BCS + i] = sp ? 1.0f : 0.0f;
    }
}

// ---------------------------------------------------------------------------
extern "C" void kernel_launch(void* const* d_in, const int* in_sizes, int n_in,
                              void* d_out, int out_size, void* d_ws, size_t ws_size,
                              hipStream_t stream)
{
    const float* x          = (const float*)d_in[0];
    const float* q_w        = (const float*)d_in[1];
    const float* q_gamma    = (const float*)d_in[2];
    const float* q_beta     = (const float*)d_in[3];
    const float* q_mean     = (const float*)d_in[4];
    const float* q_var      = (const float*)d_in[5];
    const float* k_w        = (const float*)d_in[6];
    const float* k_gamma    = (const float*)d_in[7];
    const float* k_beta     = (const float*)d_in[8];
    const float* k_mean     = (const float*)d_in[9];
    const float* k_var      = (const float*)d_in[10];
    const float* proj_w     = (const float*)d_in[11];
    const float* proj_b     = (const float*)d_in[12];
    const float* proj_gamma = (const float*)d_in[13];
    const float* proj_beta  = (const float*)d_in[14];
    const float* proj_mean  = (const float*)d_in[15];
    const float* proj_var   = (const float*)d_in[16];
    float* out = (float*)d_out;

    float* f0 = (float*)d_ws;          // q conv out; later reused as proj out
    float* f1 = f0 + NELEM;            // k conv out
    float* f2 = f1 + NELEM;            // gated y ({0,1} f32)
    unsigned char* spk = (unsigned char*)(f2 + NELEM);  // packed spikes

    const dim3 ggrid(196, 3);

    gemm_bn<false><<<ggrid, 256, 0, stream>>>(x, q_w, q_gamma, q_beta, q_mean,
                                              q_var, nullptr, f0);
    gemm_bn<false><<<ggrid, 256, 0, stream>>>(x, k_w, k_gamma, k_beta, k_mean,
                                              k_var, nullptr, f1);
    lif_spike_pack<<<(BCS + 255) / 256, 256, 0, stream>>>(f0, f1, spk);
    attn_gate<<<256, 256, 0, stream>>>(spk, f2);
    gemm_bn<true><<<ggrid, 256, 0, stream>>>(f2, proj_w, proj_gamma, proj_beta,
                                             proj_mean, proj_var, proj_b, f0);
    lif_out<<<(BCS + 255) / 256, 256, 0, stream>>>(f0, out);
}

// Round 2
// 433.514 us; speedup vs baseline: 1.0563x; 1.0563x over previous
//
#include <hip/hip_runtime.h>

#define C_DIM 384
#define S_DIM 196
#define CS_   (C_DIM * S_DIM)      // 75264 elements per (tb) slab
#define BCS   (32 * CS_)           // 2408448 elements per t-slab (B*C*S)
#define NELEM (128 * CS_)          // 9633792 total per tensor

// ---------------------------------------------------------------------------
// Fused Q+K GEMM + BN. o in [0,768): o<384 -> Q branch, else K branch.
// Y[tb, o, s] = BN( sum_c W[o,c] * X[tb, c, s] )
// 128x128 block tile, BK=8, 8x8 per-thread tile, 256 threads.
// grid (196, 6): 1176 blocks -> ~4.6 blocks/CU for latency hiding.
// ---------------------------------------------------------------------------
__global__ __launch_bounds__(256)
void qk_gemm(const float* __restrict__ X,
             const float* __restrict__ q_w, const float* __restrict__ k_w,
             const float* __restrict__ qg, const float* __restrict__ qb,
             const float* __restrict__ qm, const float* __restrict__ qv,
             const float* __restrict__ kg, const float* __restrict__ kb,
             const float* __restrict__ km, const float* __restrict__ kv,
             float* __restrict__ Yq, float* __restrict__ Yk)
{
    __shared__ float As[8][128];   // [k][o]
    __shared__ float Bs[8][128];   // [k][m]

    const int t  = threadIdx.x;
    const int m0 = blockIdx.x * 128;
    const int o0g = blockIdx.y * 128;      // [0,768)
    const bool isQ = o0g < 384;
    const int o0 = isQ ? o0g : o0g - 384;  // row within selected weight matrix

    const float* W     = isQ ? q_w : k_w;
    const float* gamma = isQ ? qg : kg;
    const float* beta  = isQ ? qb : kb;
    const float* mean  = isQ ? qm : km;
    const float* var   = isQ ? qv : kv;
    float*       Y     = isQ ? Yq : Yk;

    // A staging: thread loads float4 of W[o0 + t/2, (t&1)*4 + 8*kt ..]
    const int a_row = t >> 1;
    const int a_col = (t & 1) << 2;
    const float* Ap = W + (o0 + a_row) * C_DIM + a_col;

    // B staging: float4 of X[k0 + t/32 th row, col m0 + (t&31)*4]
    const int b_row = t >> 5;
    const int b_ch  = (t & 31) << 2;
    const int bcol  = m0 + b_ch;
    const int btb   = bcol / S_DIM;
    const int bs    = bcol - btb * S_DIM;
    const float* Bp = X + btb * CS_ + b_row * S_DIM + bs;

    const int tx = t & 15, ty = t >> 4;

    float acc[8][8];
    #pragma unroll
    for (int i = 0; i < 8; ++i)
        #pragma unroll
        for (int j = 0; j < 8; ++j) acc[i][j] = 0.0f;

    float4 aReg = *(const float4*)Ap;
    float4 bReg = *(const float4*)Bp;

    for (int kt = 0; kt < 48; ++kt) {
        As[a_col + 0][a_row] = aReg.x;
        As[a_col + 1][a_row] = aReg.y;
        As[a_col + 2][a_row] = aReg.z;
        As[a_col + 3][a_row] = aReg.w;
        *(float4*)&Bs[b_row][b_ch] = bReg;
        __syncthreads();

        if (kt < 47) {
            aReg = *(const float4*)(Ap + (kt + 1) * 8);
            bReg = *(const float4*)(Bp + (kt + 1) * 8 * S_DIM);
        }

        #pragma unroll
        for (int k = 0; k < 8; ++k) {
            float4 a0 = *(const float4*)&As[k][ty * 4];
            float4 a1 = *(const float4*)&As[k][64 + ty * 4];
            float4 b0 = *(const float4*)&Bs[k][tx * 4];
            float4 b1 = *(const float4*)&Bs[k][64 + tx * 4];
            float av[8] = {a0.x, a0.y, a0.z, a0.w, a1.x, a1.y, a1.z, a1.w};
            float bv[8] = {b0.x, b0.y, b0.z, b0.w, b1.x, b1.y, b1.z, b1.w};
            #pragma unroll
            for (int i = 0; i < 8; ++i)
                #pragma unroll
                for (int j = 0; j < 8; ++j)
                    acc[i][j] += av[i] * bv[j];
        }
        __syncthreads();
    }

    #pragma unroll
    for (int ri = 0; ri < 2; ++ri) {
        #pragma unroll
        for (int r = 0; r < 4; ++r) {
            const int i = ri * 4 + r;
            const int o = o0 + ri * 64 + ty * 4 + r;
            const float inv = gamma[o] / sqrtf(var[o] + 1e-5f);
            const float sh  = beta[o] - mean[o] * inv;
            #pragma unroll
            for (int ci = 0; ci < 2; ++ci) {
                const int col = m0 + ci * 64 + tx * 4;
                const int tb  = col / S_DIM;
                const int s2  = col - tb * S_DIM;
                float4 v;
                v.x = acc[i][ci * 4 + 0] * inv + sh;
                v.y = acc[i][ci * 4 + 1] * inv + sh;
                v.z = acc[i][ci * 4 + 2] * inv + sh;
                v.w = acc[i][ci * 4 + 3] * inv + sh;
                *(float4*)(Y + tb * CS_ + o * S_DIM + s2) = v;
            }
        }
    }
}

// ---------------------------------------------------------------------------
// LIF over t for q and k conv outputs; pack 8 spike bits per (b,c,s) element.
// bits 0..3 = q spikes t=0..3, bits 4..7 = k spikes.
// ---------------------------------------------------------------------------
__global__ __launch_bounds__(256)
void lif_spike_pack(const float* __restrict__ wsq, const float* __restrict__ wsk,
                    unsigned char* __restrict__ spk)
{
    const int i = blockIdx.x * 256 + threadIdx.x;   // over B*C*S
    if (i >= BCS) return;
    float vq = 0.0f, vk = 0.0f;
    int bits = 0;
    #pragma unroll
    for (int t = 0; t < 4; ++t) {
        const float xq = wsq[t * BCS + i];
        const float hq = vq + (xq - vq) * 0.5f;
        const int sq = (hq >= 1.0f);
        vq = sq ? 0.0f : hq;
        bits |= sq << t;

        const float xk = wsk[t * BCS + i];
        const float hk = vk + (xk - vk) * 0.5f;
        const int sk = (hk >= 1.0f);
        vk = sk ? 0.0f : hk;
        bits |= sk << (4 + t);
    }
    spk[i] = (unsigned char)bits;
}

// ---------------------------------------------------------------------------
// attn LIF (exact dyadic): per (b, head, s) sum q-spikes over 48 channels,
// run LIF with v_th=0.5, emit 4 attn bits (one per t) into attnB.
// ---------------------------------------------------------------------------
__global__ __launch_bounds__(256)
void attn_compute(const unsigned char* __restrict__ spk,
                  unsigned char* __restrict__ attnB)
{
    const int b    = blockIdx.x >> 3;
    const int head = blockIdx.x & 7;
    const int s    = threadIdx.x;
    if (s >= S_DIM) return;

    const unsigned char* sp = spk + b * CS_ + head * 48 * S_DIM + s;
    int qs[4] = {0, 0, 0, 0};
    #pragma unroll 4
    for (int c = 0; c < 48; ++c) {
        const int v = sp[c * S_DIM];
        qs[0] += v & 1;
        qs[1] += (v >> 1) & 1;
        qs[2] += (v >> 2) & 1;
        qs[3] += (v >> 3) & 1;
    }

    float va = 0.0f;
    int bits = 0;
    #pragma unroll
    for (int t = 0; t < 4; ++t) {
        const float h = va + ((float)qs[t] - va) * 0.5f;   // exact dyadic
        const int a = (h >= 0.5f);
        va = a ? 0.0f : h;
        bits |= a << t;
    }
    attnB[(b * 8 + head) * S_DIM + s] = (unsigned char)bits;
}

// ---------------------------------------------------------------------------
// Proj GEMM, split-K=2, B-tile built on the fly from spike/attn bits.
// grid (196, 3, 2); blockIdx.z selects K-half (c in [z*192, z*192+192)).
// Writes RAW partial sums (no BN) to P0 / P1.
// ---------------------------------------------------------------------------
__global__ __launch_bounds__(256)
void proj_gemm(const unsigned char* __restrict__ spk,
               const unsigned char* __restrict__ attnB,
               const float* __restrict__ W,
               float* __restrict__ P0, float* __restrict__ P1)
{
    __shared__ float As[8][128];
    __shared__ float Bs[8][128];

    const int t  = threadIdx.x;
    const int m0 = blockIdx.x * 128;
    const int o0 = blockIdx.y * 128;
    const int kh = blockIdx.z;            // K half
    float* P = kh ? P1 : P0;
    const int c_base = kh * 192;

    const int a_row = t >> 1;
    const int a_col = (t & 1) << 2;
    const float* Ap = W + (o0 + a_row) * C_DIM + c_base + a_col;

    const int b_row = t >> 5;
    const int b_ch  = (t & 31) << 2;
    const int bcol  = m0 + b_ch;
    const int btb   = bcol / S_DIM;
    const int bs    = bcol - btb * S_DIM;
    const int bb    = btb & 31;           // batch index
    const int tt    = btb >> 5;           // time index
    const unsigned char* spkp  = spk + bb * CS_ + bs;        // + c*S_DIM
    const unsigned char* attnp = attnB + bb * (8 * S_DIM) + bs; // + head*S_DIM
    const int c0 = c_base + b_row;

    const int tx = t & 15, ty = t >> 4;

    float acc[8][8];
    #pragma unroll
    for (int i = 0; i < 8; ++i)
        #pragma unroll
        for (int j = 0; j < 8; ++j) acc[i][j] = 0.0f;

    float4 aReg = *(const float4*)Ap;

    for (int kt = 0; kt < 24; ++kt) {
        const int c    = c0 + kt * 8;
        const int head = c / 48;
        const uchar4 sb = *(const uchar4*)(spkp + c * S_DIM);
        const uchar4 ab = *(const uchar4*)(attnp + head * S_DIM);

        As[a_col + 0][a_row] = aReg.x;
        As[a_col + 1][a_row] = aReg.y;
        As[a_col + 2][a_row] = aReg.z;
        As[a_col + 3][a_row] = aReg.w;
        float4 bv;
        bv.x = ((sb.x >> (4 + tt)) & (ab.x >> tt) & 1) ? 1.0f : 0.0f;
        bv.y = ((sb.y >> (4 + tt)) & (ab.y >> tt) & 1) ? 1.0f : 0.0f;
        bv.z = ((sb.z >> (4 + tt)) & (ab.z >> tt) & 1) ? 1.0f : 0.0f;
        bv.w = ((sb.w >> (4 + tt)) & (ab.w >> tt) & 1) ? 1.0f : 0.0f;
        *(float4*)&Bs[b_row][b_ch] = bv;
        __syncthreads();

        if (kt < 23)
            aReg = *(const float4*)(Ap + (kt + 1) * 8);

        #pragma unroll
        for (int k = 0; k < 8; ++k) {
            float4 a0 = *(const float4*)&As[k][ty * 4];
            float4 a1 = *(const float4*)&As[k][64 + ty * 4];
            float4 b0 = *(const float4*)&Bs[k][tx * 4];
            float4 b1 = *(const float4*)&Bs[k][64 + tx * 4];
            float av[8] = {a0.x, a0.y, a0.z, a0.w, a1.x, a1.y, a1.z, a1.w};
            float bw[8] = {b0.x, b0.y, b0.z, b0.w, b1.x, b1.y, b1.z, b1.w};
            #pragma unroll
            for (int i = 0; i < 8; ++i)
                #pragma unroll
                for (int j = 0; j < 8; ++j)
                    acc[i][j] += av[i] * bw[j];
        }
        __syncthreads();
    }

    // raw partial epilogue
    #pragma unroll
    for (int ri = 0; ri < 2; ++ri) {
        #pragma unroll
        for (int r = 0; r < 4; ++r) {
            const int i = ri * 4 + r;
            const int o = o0 + ri * 64 + ty * 4 + r;
            #pragma unroll
            for (int ci = 0; ci < 2; ++ci) {
                const int col = m0 + ci * 64 + tx * 4;
                const int tb  = col / S_DIM;
                const int s2  = col - tb * S_DIM;
                float4 v;
                v.x = acc[i][ci * 4 + 0];
                v.y = acc[i][ci * 4 + 1];
                v.z = acc[i][ci * 4 + 2];
                v.w = acc[i][ci * 4 + 3];
                *(float4*)(P + tb * CS_ + o * S_DIM + s2) = v;
            }
        }
    }
}

// ---------------------------------------------------------------------------
// Final: sum split-K partials, add bias, BN, LIF over t -> spikes to d_out.
// ---------------------------------------------------------------------------
__global__ __launch_bounds__(256)
void bn_lif_out(const float* __restrict__ P0, const float* __restrict__ P1,
                const float* __restrict__ bias,
                const float* __restrict__ gamma, const float* __restrict__ beta,
                const float* __restrict__ mean,  const float* __restrict__ var,
                float* __restrict__ out)
{
    const int i = blockIdx.x * 256 + threadIdx.x;   // over B*C*S
    if (i >= BCS) return;
    const int o = (i % CS_) / S_DIM;
    const float inv = gamma[o] / sqrtf(var[o] + 1e-5f);
    const float sh  = beta[o] - mean[o] * inv;
    const float bv  = bias[o];

    float v = 0.0f;
    #pragma unroll
    for (int t = 0; t < 4; ++t) {
        const float z = (P0[t * BCS + i] + P1[t * BCS + i] + bv) * inv + sh;
        const float h = v + (z - v) * 0.5f;
        const int sp = (h >= 1.0f);
        v = sp ? 0.0f : h;
        out[t * BCS + i] = sp ? 1.0f : 0.0f;
    }
}

// ---------------------------------------------------------------------------
extern "C" void kernel_launch(void* const* d_in, const int* in_sizes, int n_in,
                              void* d_out, int out_size, void* d_ws, size_t ws_size,
                              hipStream_t stream)
{
    const float* x          = (const float*)d_in[0];
    const float* q_w        = (const float*)d_in[1];
    const float* q_gamma    = (const float*)d_in[2];
    const float* q_beta     = (const float*)d_in[3];
    const float* q_mean     = (const float*)d_in[4];
    const float* q_var      = (const float*)d_in[5];
    const float* k_w        = (const float*)d_in[6];
    const float* k_gamma    = (const float*)d_in[7];
    const float* k_beta     = (const float*)d_in[8];
    const float* k_mean     = (const float*)d_in[9];
    const float* k_var      = (const float*)d_in[10];
    const float* proj_w     = (const float*)d_in[11];
    const float* proj_b     = (const float*)d_in[12];
    const float* proj_gamma = (const float*)d_in[13];
    const float* proj_beta  = (const float*)d_in[14];
    const float* proj_mean  = (const float*)d_in[15];
    const float* proj_var   = (const float*)d_in[16];
    float* out = (float*)d_out;

    float* f0 = (float*)d_ws;                  // q conv out; later proj partial 0
    float* f1 = f0 + NELEM;                    // k conv out; later proj partial 1
    unsigned char* spk   = (unsigned char*)(f1 + NELEM);  // packed spikes (BCS bytes)
    unsigned char* attnB = spk + BCS;                      // attn bits (50 KB)

    qk_gemm<<<dim3(196, 6), 256, 0, stream>>>(x, q_w, k_w,
                                              q_gamma, q_beta, q_mean, q_var,
                                              k_gamma, k_beta, k_mean, k_var,
                                              f0, f1);
    lif_spike_pack<<<(BCS + 255) / 256, 256, 0, stream>>>(f0, f1, spk);
    attn_compute<<<256, 256, 0, stream>>>(spk, attnB);
    proj_gemm<<<dim3(196, 3, 2), 256, 0, stream>>>(spk, attnB, proj_w, f0, f1);
    bn_lif_out<<<(BCS + 255) / 256, 256, 0, stream>>>(f0, f1, proj_b,
                                                      proj_gamma, proj_beta,
                                                      proj_mean, proj_var, out);
}

// Round 3
// 281.249 us; speedup vs baseline: 1.6282x; 1.5414x over previous
//
#include <hip/hip_runtime.h>

#define C_DIM 384
#define S_DIM 196
#define CS_   (C_DIM * S_DIM)      // 75264 elements per (tb) slab
#define BCS   (32 * CS_)           // 2408448 elements per t-slab (B*C*S)
#define NELEM (128 * CS_)          // 9633792 total per tensor
#define M_TOT 25088                // 128 * 196 spatial columns

typedef _Float16 half8  __attribute__((ext_vector_type(8)));
typedef float    floatx4 __attribute__((ext_vector_type(4)));

// async 16B/lane global->LDS copy; lds base must be wave-uniform, HW adds lane*16.
__device__ __forceinline__ void gl_lds16(const _Float16* g, _Float16* l) {
    __builtin_amdgcn_global_load_lds(
        (const __attribute__((address_space(1))) unsigned int*)g,
        (__attribute__((address_space(3))) unsigned int*)l, 16, 0, 0);
}

// ---------------------------------------------------------------------------
// Split weights into fp16 hi/lo(x4096) planes; also precompute BN inv/sh for
// the fused qk output rows (768).
// ---------------------------------------------------------------------------
__global__ __launch_bounds__(256)
void split_w(const float* __restrict__ qw, const float* __restrict__ kw,
             const float* __restrict__ pw,
             const float* qg, const float* qb, const float* qm, const float* qv,
             const float* kg, const float* kb, const float* km, const float* kv,
             _Float16* __restrict__ Wq0, _Float16* __restrict__ Wq1,
             _Float16* __restrict__ Wp0, _Float16* __restrict__ Wp1,
             float2* __restrict__ invsh)
{
    const int i = blockIdx.x * 256 + threadIdx.x;
    const int NQ = 768 * C_DIM;
    if (i < NQ) {
        const int o = i / C_DIM, c = i - o * C_DIM;
        const float v = (o < 384) ? qw[o * C_DIM + c] : kw[(o - 384) * C_DIM + c];
        const _Float16 h0 = (_Float16)v;
        Wq0[i] = h0;
        Wq1[i] = (_Float16)((v - (float)h0) * 4096.0f);
    } else if (i < NQ + C_DIM * C_DIM) {
        const int j = i - NQ;
        const float v = pw[j];
        const _Float16 h0 = (_Float16)v;
        Wp0[j] = h0;
        Wp1[j] = (_Float16)((v - (float)h0) * 4096.0f);
    }
    if (i < 768) {
        float g, b, m, vv;
        if (i < 384) { g = qg[i]; b = qb[i]; m = qm[i]; vv = qv[i]; }
        else         { g = kg[i-384]; b = kb[i-384]; m = km[i-384]; vv = kv[i-384]; }
        const float inv = g / sqrtf(vv + 1e-5f);
        invsh[i] = make_float2(inv, b - m * inv);
    }
}

// ---------------------------------------------------------------------------
// Split + transpose X: [tb][c][s] fp32 -> Xt0/Xt1 [m=tb*196+s][c] fp16 planes.
// Block = (tb, 32-channel chunk); LDS tile transpose, +pad row stride 201.
// ---------------------------------------------------------------------------
__global__ __launch_bounds__(256)
void split_x(const float* __restrict__ X,
             _Float16* __restrict__ X0, _Float16* __restrict__ X1)
{
    __shared__ float tile[32][201];
    const int tb = blockIdx.x;
    const int c0 = blockIdx.y * 32;
    const int t  = threadIdx.x;
    for (int idx = t; idx < 32 * S_DIM; idx += 256) {
        const int cc = idx / S_DIM, s = idx - cc * S_DIM;
        tile[cc][s] = X[(size_t)tb * CS_ + (c0 + cc) * S_DIM + s];
    }
    __syncthreads();
    for (int idx = t; idx < 32 * S_DIM; idx += 256) {
        const int s = idx >> 5, cc = idx & 31;
        const float v = tile[cc][s];
        const _Float16 h0 = (_Float16)v;
        const size_t off = (size_t)(tb * S_DIM + s) * C_DIM + c0 + cc;
        X0[off] = h0;
        X1[off] = (_Float16)((v - (float)h0) * 4096.0f);
    }
}

// ---------------------------------------------------------------------------
// MFMA GEMM, m97 structure: 128x128 tile, BK=32, 4 waves each 64x64 quadrant,
// 16x16x32 f16 MFMA. Multi-pass split accumulation: passes [0..scale_after]
// are lo-terms (carry 2^12); after pass scale_after, acc *= 2^-12; remaining
// passes are hi-terms. K=384 fixed (12 k-iters per pass).
// BN_EPI: apply invsh and split rows <384 -> Y0, >=384 -> Y1 (fused qk).
// else: raw fp32 acc to Y0.
// ---------------------------------------------------------------------------
template<bool BN_EPI>
__global__ __launch_bounds__(256)
void mfma_gemm(const _Float16* __restrict__ A0, const _Float16* __restrict__ A1,
               const _Float16* __restrict__ A2,
               const _Float16* __restrict__ B0, const _Float16* __restrict__ B1,
               const _Float16* __restrict__ B2,
               const int npass, const int scale_after,
               const float2* __restrict__ invsh,
               float* __restrict__ Y0, float* __restrict__ Y1)
{
    __shared__ __align__(16) _Float16 As[128 * 32];
    __shared__ __align__(16) _Float16 Bs[128 * 32];

    const int t    = threadIdx.x;
    const int wave = t >> 6, lane = t & 63;
    const int m0 = blockIdx.x * 128;
    const int o0 = blockIdx.y * 128;

    // staging: wave stages rows [wave*32, wave*32+32) of both tiles, 2 issues each
    const int sRow = lane >> 2;          // 0..15 within a 16-row issue
    const int sCol = (lane & 3) << 3;    // k offset in halves (0,8,16,24)
    const int wR   = wave * 32;

    const int lo = lane & 15, quad = lane >> 4;
    const int oq = (wave >> 1) * 64, mq = (wave & 1) * 64;

    floatx4 acc[4][4];
    #pragma unroll
    for (int i = 0; i < 4; ++i)
        #pragma unroll
        for (int j = 0; j < 4; ++j) acc[i][j] = (floatx4)0.0f;

    for (int p = 0; p < npass; ++p) {
        const _Float16* Ap = (p == 0) ? A0 : ((p == 1) ? A1 : A2);
        const _Float16* Bp = (p == 0) ? B0 : ((p == 1) ? B1 : B2);
        for (int kt = 0; kt < 12; ++kt) {
            __syncthreads();   // previous tile fully consumed
            const int kb = kt * 32;
            #pragma unroll
            for (int u = 0; u < 2; ++u) {
                const int R = wR + u * 16;
                gl_lds16(Ap + (size_t)(o0 + R + sRow) * C_DIM + kb + sCol, &As[R * 32]);
                gl_lds16(Bp + (size_t)(m0 + R + sRow) * C_DIM + kb + sCol, &Bs[R * 32]);
            }
            __syncthreads();   // staging drained (vmcnt0 before barrier)

            half8 aF[4], bF[4];
            #pragma unroll
            for (int i = 0; i < 4; ++i)
                aF[i] = *(const half8*)&As[(oq + i * 16 + lo) * 32 + quad * 8];
            #pragma unroll
            for (int j = 0; j < 4; ++j)
                bF[j] = *(const half8*)&Bs[(mq + j * 16 + lo) * 32 + quad * 8];
            #pragma unroll
            for (int i = 0; i < 4; ++i)
                #pragma unroll
                for (int j = 0; j < 4; ++j)
                    acc[i][j] = __builtin_amdgcn_mfma_f32_16x16x32_f16(
                        aF[i], bF[j], acc[i][j], 0, 0, 0);
        }
        if (p == scale_after) {
            #pragma unroll
            for (int i = 0; i < 4; ++i)
                #pragma unroll
                for (int j = 0; j < 4; ++j)
                    acc[i][j] = acc[i][j] * (1.0f / 4096.0f);
        }
    }

    // epilogue: C/D layout col=lane&15, row=quad*4+reg
    #pragma unroll
    for (int i = 0; i < 4; ++i) {
        #pragma unroll
        for (int r = 0; r < 4; ++r) {
            const int o = o0 + oq + i * 16 + quad * 4 + r;
            float inv = 1.0f, sh = 0.0f;
            float* base = Y0;
            int orow = o;
            if (BN_EPI) {
                const float2 is = invsh[o];
                inv = is.x; sh = is.y;
                if (o >= 384) { base = Y1; orow = o - 384; }
            }
            #pragma unroll
            for (int j = 0; j < 4; ++j) {
                const int m  = m0 + mq + j * 16 + lo;
                const int tb = m / S_DIM;
                const int s  = m - tb * S_DIM;
                const float v = BN_EPI ? (acc[i][j][r] * inv + sh) : acc[i][j][r];
                base[(size_t)tb * CS_ + orow * S_DIM + s] = v;
            }
        }
    }
}

// ---------------------------------------------------------------------------
// LIF over t for q and k conv outputs; pack 8 spike bits per (b,c,s) element.
// bits 0..3 = q spikes t=0..3, bits 4..7 = k spikes.
// ---------------------------------------------------------------------------
__global__ __launch_bounds__(256)
void lif_spike_pack(const float* __restrict__ wsq, const float* __restrict__ wsk,
                    unsigned char* __restrict__ spk)
{
    const int i = blockIdx.x * 256 + threadIdx.x;   // over B*C*S
    if (i >= BCS) return;
    float vq = 0.0f, vk = 0.0f;
    int bits = 0;
    #pragma unroll
    for (int t = 0; t < 4; ++t) {
        const float xq = wsq[t * BCS + i];
        const float hq = vq + (xq - vq) * 0.5f;
        const int sq = (hq >= 1.0f);
        vq = sq ? 0.0f : hq;
        bits |= sq << t;

        const float xk = wsk[t * BCS + i];
        const float hk = vk + (xk - vk) * 0.5f;
        const int sk = (hk >= 1.0f);
        vk = sk ? 0.0f : hk;
        bits |= sk << (4 + t);
    }
    spk[i] = (unsigned char)bits;
}

// ---------------------------------------------------------------------------
// attn LIF (exact dyadic): per (b, head, s) sum q-spikes over 48 channels,
// run LIF with v_th=0.5, emit 4 attn bits (one per t) into attnB.
// ---------------------------------------------------------------------------
__global__ __launch_bounds__(256)
void attn_compute(const unsigned char* __restrict__ spk,
                  unsigned char* __restrict__ attnB)
{
    const int b    = blockIdx.x >> 3;
    const int head = blockIdx.x & 7;
    const int s    = threadIdx.x;
    if (s >= S_DIM) return;

    const unsigned char* sp = spk + b * CS_ + head * 48 * S_DIM + s;
    int qs[4] = {0, 0, 0, 0};
    #pragma unroll 4
    for (int c = 0; c < 48; ++c) {
        const int v = sp[c * S_DIM];
        qs[0] += v & 1;
        qs[1] += (v >> 1) & 1;
        qs[2] += (v >> 2) & 1;
        qs[3] += (v >> 3) & 1;
    }

    float va = 0.0f;
    int bits = 0;
    #pragma unroll
    for (int t = 0; t < 4; ++t) {
        const float h = va + ((float)qs[t] - va) * 0.5f;   // exact dyadic
        const int a = (h >= 0.5f);
        va = a ? 0.0f : h;
        bits |= a << t;
    }
    attnB[(b * 8 + head) * S_DIM + s] = (unsigned char)bits;
}

// ---------------------------------------------------------------------------
// Build proj GEMM's B operand: Yt[m=tb*196+s][c] fp16 = attn_bit & k_spike_bit.
// LDS transpose for coalesced 2B writes.
// ---------------------------------------------------------------------------
__global__ __launch_bounds__(256)
void build_y(const unsigned char* __restrict__ spk,
             const unsigned char* __restrict__ attnB,
             unsigned short* __restrict__ Yt)
{
    __shared__ unsigned char tile[128][200];
    const int tb = blockIdx.x;          // t*32 + b
    const int b  = tb & 31, tt = tb >> 5;
    const int c0 = blockIdx.y * 128;
    const int t  = threadIdx.x;
    for (int idx = t; idx < 128 * S_DIM; idx += 256) {
        const int cc = idx / S_DIM, s = idx - cc * S_DIM;
        const int c = c0 + cc;
        const int kbit = (spk[b * CS_ + c * S_DIM + s] >> (4 + tt)) & 1;
        const int abit = (attnB[(b * 8 + c / 48) * S_DIM + s] >> tt) & 1;
        tile[cc][s] = (unsigned char)(kbit & abit);
    }
    __syncthreads();
    for (int idx = t; idx < 128 * S_DIM; idx += 256) {
        const int s = idx >> 7, cc = idx & 127;
        Yt[(size_t)(tb * S_DIM + s) * C_DIM + c0 + cc] = tile[cc][s] ? 0x3C00 : 0;
    }
}

// ---------------------------------------------------------------------------
// Final: bias, BN, LIF over t -> spikes to d_out.
// ---------------------------------------------------------------------------
__global__ __launch_bounds__(256)
void bn_lif_out(const float* __restrict__ P, const float* __restrict__ bias,
                const float* __restrict__ gamma, const float* __restrict__ beta,
                const float* __restrict__ mean,  const float* __restrict__ var,
                float* __restrict__ out)
{
    const int i = blockIdx.x * 256 + threadIdx.x;   // over B*C*S
    if (i >= BCS) return;
    const int o = (i % CS_) / S_DIM;
    const float inv = gamma[o] / sqrtf(var[o] + 1e-5f);
    const float sh  = beta[o] - mean[o] * inv;
    const float bv  = bias[o];

    float v = 0.0f;
    #pragma unroll
    for (int t = 0; t < 4; ++t) {
        const float z = (P[t * BCS + i] + bv) * inv + sh;
        const float h = v + (z - v) * 0.5f;
        const int sp = (h >= 1.0f);
        v = sp ? 0.0f : h;
        out[t * BCS + i] = sp ? 1.0f : 0.0f;
    }
}

// ---------------------------------------------------------------------------
extern "C" void kernel_launch(void* const* d_in, const int* in_sizes, int n_in,
                              void* d_out, int out_size, void* d_ws, size_t ws_size,
                              hipStream_t stream)
{
    const float* x          = (const float*)d_in[0];
    const float* q_w        = (const float*)d_in[1];
    const float* q_gamma    = (const float*)d_in[2];
    const float* q_beta     = (const float*)d_in[3];
    const float* q_mean     = (const float*)d_in[4];
    const float* q_var      = (const float*)d_in[5];
    const float* k_w        = (const float*)d_in[6];
    const float* k_gamma    = (const float*)d_in[7];
    const float* k_beta     = (const float*)d_in[8];
    const float* k_mean     = (const float*)d_in[9];
    const float* k_var      = (const float*)d_in[10];
    const float* proj_w     = (const float*)d_in[11];
    const float* proj_b     = (const float*)d_in[12];
    const float* proj_gamma = (const float*)d_in[13];
    const float* proj_beta  = (const float*)d_in[14];
    const float* proj_mean  = (const float*)d_in[15];
    const float* proj_var   = (const float*)d_in[16];
    float* out = (float*)d_out;

    // workspace layout (117.38 MB total):
    float*    f0 = (float*)d_ws;            // Yq; later proj raw output P
    float*    f1 = f0 + NELEM;              // Yk
    _Float16* h0 = (_Float16*)(f1 + NELEM); // Xt0; later Yt (binary fp16)
    _Float16* h1 = h0 + NELEM;              // Xt1; later spk+attnB region
    _Float16* Wq0 = h1 + NELEM;             // 768x384
    _Float16* Wq1 = Wq0 + 768 * C_DIM;
    _Float16* Wp0 = Wq1 + 768 * C_DIM;      // 384x384
    _Float16* Wp1 = Wp0 + C_DIM * C_DIM;
    float2*   invsh = (float2*)(Wp1 + C_DIM * C_DIM);   // 768 entries
    unsigned char* spk   = (unsigned char*)h1;          // BCS bytes
    unsigned char* attnB = spk + BCS;                   // 50176 bytes

    split_w<<<1728, 256, 0, stream>>>(q_w, k_w, proj_w,
                                      q_gamma, q_beta, q_mean, q_var,
                                      k_gamma, k_beta, k_mean, k_var,
                                      Wq0, Wq1, Wp0, Wp1, invsh);
    split_x<<<dim3(128, 12), 256, 0, stream>>>(x, h0, h1);

    // qk: pass0 = a0*b1(lo), pass1 = a1*b0(lo), scale 2^-12, pass2 = a0*b0(hi)
    mfma_gemm<true><<<dim3(196, 6), 256, 0, stream>>>(
        Wq0, Wq1, Wq0, h1, h0, h0, 3, 1, invsh, f0, f1);

    lif_spike_pack<<<(BCS + 255) / 256, 256, 0, stream>>>(f0, f1, spk);
    attn_compute<<<256, 256, 0, stream>>>(spk, attnB);
    build_y<<<dim3(128, 3), 256, 0, stream>>>(spk, attnB, (unsigned short*)h0);

    // proj: pass0 = w1*y(lo), scale 2^-12, pass1 = w0*y(hi); raw fp32 out
    mfma_gemm<false><<<dim3(196, 3), 256, 0, stream>>>(
        Wp1, Wp0, Wp0, h0, h0, h0, 2, 0, nullptr, f0, nullptr);

    bn_lif_out<<<(BCS + 255) / 256, 256, 0, stream>>>(f0, proj_b,
                                                      proj_gamma, proj_beta,
                                                      proj_mean, proj_var, out);
}

// Round 4
// 252.761 us; speedup vs baseline: 1.8117x; 1.1127x over previous
//
#include <hip/hip_runtime.h>

#define C_DIM 384
#define S_DIM 196
#define CS_   (C_DIM * S_DIM)      // 75264 elements per (tb) slab
#define BCS   (32 * CS_)           // 2408448 elements per t-slab (B*C*S)
#define NELEM (128 * CS_)          // 9633792 total per tensor

typedef _Float16 half8  __attribute__((ext_vector_type(8)));
typedef float    floatx4 __attribute__((ext_vector_type(4)));

// async 16B/lane global->LDS copy; lds base must be wave-uniform, HW adds lane*16.
__device__ __forceinline__ void gl_lds16(const _Float16* g, _Float16* l) {
    __builtin_amdgcn_global_load_lds(
        (const __attribute__((address_space(1))) unsigned int*)g,
        (__attribute__((address_space(3))) unsigned int*)l, 16, 0, 0);
}

// ---------------------------------------------------------------------------
// Split weights into fp16 hi/lo(x4096) planes; precompute BN inv/sh (768 rows).
// ---------------------------------------------------------------------------
__global__ __launch_bounds__(256)
void split_w(const float* __restrict__ qw, const float* __restrict__ kw,
             const float* __restrict__ pw,
             const float* qg, const float* qb, const float* qm, const float* qv,
             const float* kg, const float* kb, const float* km, const float* kv,
             _Float16* __restrict__ Wq0, _Float16* __restrict__ Wq1,
             _Float16* __restrict__ Wp0, _Float16* __restrict__ Wp1,
             float2* __restrict__ invsh)
{
    const int i = blockIdx.x * 256 + threadIdx.x;
    const int NQ = 768 * C_DIM;
    if (i < NQ) {
        const int o = i / C_DIM, c = i - o * C_DIM;
        const float v = (o < 384) ? qw[o * C_DIM + c] : kw[(o - 384) * C_DIM + c];
        const _Float16 h0 = (_Float16)v;
        Wq0[i] = h0;
        Wq1[i] = (_Float16)((v - (float)h0) * 4096.0f);
    } else if (i < NQ + C_DIM * C_DIM) {
        const int j = i - NQ;
        const float v = pw[j];
        const _Float16 h0 = (_Float16)v;
        Wp0[j] = h0;
        Wp1[j] = (_Float16)((v - (float)h0) * 4096.0f);
    }
    if (i < 768) {
        float g, b, m, vv;
        if (i < 384) { g = qg[i]; b = qb[i]; m = qm[i]; vv = qv[i]; }
        else         { g = kg[i-384]; b = kb[i-384]; m = km[i-384]; vv = kv[i-384]; }
        const float inv = g / sqrtf(vv + 1e-5f);
        invsh[i] = make_float2(inv, b - m * inv);
    }
}

// ---------------------------------------------------------------------------
// Split + transpose X: [tb][c][s] fp32 -> X0/X1 [m=tb*196+s][c] fp16 planes.
// ---------------------------------------------------------------------------
__global__ __launch_bounds__(256)
void split_x(const float* __restrict__ X,
             _Float16* __restrict__ X0, _Float16* __restrict__ X1)
{
    __shared__ float tile[32][201];
    const int tb = blockIdx.x;
    const int c0 = blockIdx.y * 32;
    const int t  = threadIdx.x;
    for (int idx = t; idx < 32 * S_DIM; idx += 256) {
        const int cc = idx / S_DIM, s = idx - cc * S_DIM;
        tile[cc][s] = X[(size_t)tb * CS_ + (c0 + cc) * S_DIM + s];
    }
    __syncthreads();
    for (int idx = t; idx < 32 * S_DIM; idx += 256) {
        const int s = idx >> 5, cc = idx & 31;
        const float v = tile[cc][s];
        const _Float16 h0 = (_Float16)v;
        const size_t off = (size_t)(tb * S_DIM + s) * C_DIM + c0 + cc;
        X0[off] = h0;
        X1[off] = (_Float16)((v - (float)h0) * 4096.0f);
    }
}

// ---------------------------------------------------------------------------
// Fused-split qk GEMM (single K-loop): acc += A0*B1 + A1*B0 + (4096*A0)*B0,
// result = acc * 2^-12, then BN. 128x128 tile, BK=32, 16x16x32 f16 MFMA,
// 4 waves = 64x64 quadrants. XOR-swizzled LDS chunks (2-way banks = free).
// rows <384 -> Yq, >=384 -> Yk.
// ---------------------------------------------------------------------------
__global__ __launch_bounds__(256, 3)
void qk_mfma(const _Float16* __restrict__ A0, const _Float16* __restrict__ A1,
             const _Float16* __restrict__ B0, const _Float16* __restrict__ B1,
             const float2* __restrict__ invsh,
             float* __restrict__ Yq, float* __restrict__ Yk)
{
    __shared__ __align__(16) _Float16 As0[128 * 32];
    __shared__ __align__(16) _Float16 As1[128 * 32];
    __shared__ __align__(16) _Float16 Bs0[128 * 32];
    __shared__ __align__(16) _Float16 Bs1[128 * 32];

    const int t    = threadIdx.x;
    const int wave = t >> 6, lane = t & 63;
    const int m0 = blockIdx.x * 128;
    const int o0 = blockIdx.y * 128;

    // staging: lane -> row sRow(+16u), swizzled global chunk
    const int sRow   = lane >> 2;
    const int gChunk = (lane & 3) ^ ((sRow >> 1) & 3);
    const int sCol   = gChunk << 3;            // halves
    const int wR     = wave * 32;

    const int lo = lane & 15, quad = lane >> 4;
    const int oq = (wave >> 1) * 64, mq = (wave & 1) * 64;
    const int rdC = (quad ^ ((lo >> 1) & 3)) << 3;   // un-swizzled read chunk

    floatx4 acc[4][4];
    #pragma unroll
    for (int i = 0; i < 4; ++i)
        #pragma unroll
        for (int j = 0; j < 4; ++j) acc[i][j] = (floatx4)0.0f;

    for (int kt = 0; kt < 12; ++kt) {
        __syncthreads();
        const int kb = kt * 32;
        #pragma unroll
        for (int u = 0; u < 2; ++u) {
            const int R = wR + u * 16;
            const size_t ga = (size_t)(o0 + R + sRow) * C_DIM + kb + sCol;
            const size_t gb = (size_t)(m0 + R + sRow) * C_DIM + kb + sCol;
            gl_lds16(A0 + ga, &As0[R * 32]);
            gl_lds16(A1 + ga, &As1[R * 32]);
            gl_lds16(B0 + gb, &Bs0[R * 32]);
            gl_lds16(B1 + gb, &Bs1[R * 32]);
        }
        __syncthreads();

        half8 a0F[4], a1F[4], b0F[4], b1F[4];
        #pragma unroll
        for (int i = 0; i < 4; ++i) {
            const int ra = (oq + i * 16 + lo) * 32 + rdC;
            a0F[i] = *(const half8*)&As0[ra];
            a1F[i] = *(const half8*)&As1[ra];
        }
        #pragma unroll
        for (int j = 0; j < 4; ++j) {
            const int rb = (mq + j * 16 + lo) * 32 + rdC;
            b0F[j] = *(const half8*)&Bs0[rb];
            b1F[j] = *(const half8*)&Bs1[rb];
        }
        #pragma unroll
        for (int i = 0; i < 4; ++i) {
            const half8 aS = a0F[i] * (_Float16)4096.0f;   // exact pow2 scale
            #pragma unroll
            for (int j = 0; j < 4; ++j) {
                acc[i][j] = __builtin_amdgcn_mfma_f32_16x16x32_f16(
                    a0F[i], b1F[j], acc[i][j], 0, 0, 0);
                acc[i][j] = __builtin_amdgcn_mfma_f32_16x16x32_f16(
                    a1F[i], b0F[j], acc[i][j], 0, 0, 0);
                acc[i][j] = __builtin_amdgcn_mfma_f32_16x16x32_f16(
                    aS,     b0F[j], acc[i][j], 0, 0, 0);
            }
        }
    }

    // epilogue: C/D layout col=lane&15, row=quad*4+reg; scale 2^-12 + BN
    #pragma unroll
    for (int i = 0; i < 4; ++i) {
        #pragma unroll
        for (int r = 0; r < 4; ++r) {
            const int o = o0 + oq + i * 16 + quad * 4 + r;
            const float2 is = invsh[o];
            const float inv = is.x * (1.0f / 4096.0f);
            const float sh  = is.y;
            float* base = Yq;
            int orow = o;
            if (o >= 384) { base = Yk; orow = o - 384; }
            #pragma unroll
            for (int j = 0; j < 4; ++j) {
                const int m  = m0 + mq + j * 16 + lo;
                const int tb = m / S_DIM;
                const int s  = m - tb * S_DIM;
                base[(size_t)tb * CS_ + orow * S_DIM + s] = acc[i][j][r] * inv + sh;
            }
        }
    }
}

// ---------------------------------------------------------------------------
// Fused-split proj GEMM: acc += A1*Y + (4096*A0)*Y, out = acc * 2^-12 (raw).
// Y (binary fp16) staged once per k-iter.
// ---------------------------------------------------------------------------
__global__ __launch_bounds__(256, 3)
void proj_mfma(const _Float16* __restrict__ A0, const _Float16* __restrict__ A1,
               const _Float16* __restrict__ B0, float* __restrict__ Y0)
{
    __shared__ __align__(16) _Float16 As0[128 * 32];
    __shared__ __align__(16) _Float16 As1[128 * 32];
    __shared__ __align__(16) _Float16 Bs0[128 * 32];

    const int t    = threadIdx.x;
    const int wave = t >> 6, lane = t & 63;
    const int m0 = blockIdx.x * 128;
    const int o0 = blockIdx.y * 128;

    const int sRow   = lane >> 2;
    const int gChunk = (lane & 3) ^ ((sRow >> 1) & 3);
    const int sCol   = gChunk << 3;
    const int wR     = wave * 32;

    const int lo = lane & 15, quad = lane >> 4;
    const int oq = (wave >> 1) * 64, mq = (wave & 1) * 64;
    const int rdC = (quad ^ ((lo >> 1) & 3)) << 3;

    floatx4 acc[4][4];
    #pragma unroll
    for (int i = 0; i < 4; ++i)
        #pragma unroll
        for (int j = 0; j < 4; ++j) acc[i][j] = (floatx4)0.0f;

    for (int kt = 0; kt < 12; ++kt) {
        __syncthreads();
        const int kb = kt * 32;
        #pragma unroll
        for (int u = 0; u < 2; ++u) {
            const int R = wR + u * 16;
            const size_t ga = (size_t)(o0 + R + sRow) * C_DIM + kb + sCol;
            const size_t gb = (size_t)(m0 + R + sRow) * C_DIM + kb + sCol;
            gl_lds16(A0 + ga, &As0[R * 32]);
            gl_lds16(A1 + ga, &As1[R * 32]);
            gl_lds16(B0 + gb, &Bs0[R * 32]);
        }
        __syncthreads();

        half8 a0F[4], a1F[4], bF[4];
        #pragma unroll
        for (int i = 0; i < 4; ++i) {
            const int ra = (oq + i * 16 + lo) * 32 + rdC;
            a0F[i] = *(const half8*)&As0[ra];
            a1F[i] = *(const half8*)&As1[ra];
        }
        #pragma unroll
        for (int j = 0; j < 4; ++j)
            bF[j] = *(const half8*)&Bs0[(mq + j * 16 + lo) * 32 + rdC];

        #pragma unroll
        for (int i = 0; i < 4; ++i) {
            const half8 aS = a0F[i] * (_Float16)4096.0f;
            #pragma unroll
            for (int j = 0; j < 4; ++j) {
                acc[i][j] = __builtin_amdgcn_mfma_f32_16x16x32_f16(
                    a1F[i], bF[j], acc[i][j], 0, 0, 0);
                acc[i][j] = __builtin_amdgcn_mfma_f32_16x16x32_f16(
                    aS,     bF[j], acc[i][j], 0, 0, 0);
            }
        }
    }

    #pragma unroll
    for (int i = 0; i < 4; ++i) {
        #pragma unroll
        for (int r = 0; r < 4; ++r) {
            const int o = o0 + oq + i * 16 + quad * 4 + r;
            #pragma unroll
            for (int j = 0; j < 4; ++j) {
                const int m  = m0 + mq + j * 16 + lo;
                const int tb = m / S_DIM;
                const int s  = m - tb * S_DIM;
                Y0[(size_t)tb * CS_ + o * S_DIM + s] = acc[i][j][r] * (1.0f / 4096.0f);
            }
        }
    }
}

// ---------------------------------------------------------------------------
// LIF over t for q and k conv outputs; pack 8 spike bits per (b,c,s) element.
// ---------------------------------------------------------------------------
__global__ __launch_bounds__(256)
void lif_spike_pack(const float* __restrict__ wsq, const float* __restrict__ wsk,
                    unsigned char* __restrict__ spk)
{
    const int i = blockIdx.x * 256 + threadIdx.x;   // over B*C*S
    if (i >= BCS) return;
    float vq = 0.0f, vk = 0.0f;
    int bits = 0;
    #pragma unroll
    for (int t = 0; t < 4; ++t) {
        const float xq = wsq[t * BCS + i];
        const float hq = vq + (xq - vq) * 0.5f;
        const int sq = (hq >= 1.0f);
        vq = sq ? 0.0f : hq;
        bits |= sq << t;

        const float xk = wsk[t * BCS + i];
        const float hk = vk + (xk - vk) * 0.5f;
        const int sk = (hk >= 1.0f);
        vk = sk ? 0.0f : hk;
        bits |= sk << (4 + t);
    }
    spk[i] = (unsigned char)bits;
}

// ---------------------------------------------------------------------------
// attn LIF (exact dyadic) per (b, head, s): sum q-spikes over 48 channels,
// LIF v_th=0.5, emit 4 attn bits into attnB.
// ---------------------------------------------------------------------------
__global__ __launch_bounds__(256)
void attn_compute(const unsigned char* __restrict__ spk,
                  unsigned char* __restrict__ attnB)
{
    const int b    = blockIdx.x >> 3;
    const int head = blockIdx.x & 7;
    const int s    = threadIdx.x;
    if (s >= S_DIM) return;

    const unsigned char* sp = spk + b * CS_ + head * 48 * S_DIM + s;
    int qs[4] = {0, 0, 0, 0};
    #pragma unroll 4
    for (int c = 0; c < 48; ++c) {
        const int v = sp[c * S_DIM];
        qs[0] += v & 1;
        qs[1] += (v >> 1) & 1;
        qs[2] += (v >> 2) & 1;
        qs[3] += (v >> 3) & 1;
    }

    float va = 0.0f;
    int bits = 0;
    #pragma unroll
    for (int t = 0; t < 4; ++t) {
        const float h = va + ((float)qs[t] - va) * 0.5f;   // exact dyadic
        const int a = (h >= 0.5f);
        va = a ? 0.0f : h;
        bits |= a << t;
    }
    attnB[(b * 8 + head) * S_DIM + s] = (unsigned char)bits;
}

// ---------------------------------------------------------------------------
// Build proj B operand: Yt[m=tb*196+s][c] fp16 = attn_bit & k_spike_bit.
// ---------------------------------------------------------------------------
__global__ __launch_bounds__(256)
void build_y(const unsigned char* __restrict__ spk,
             const unsigned char* __restrict__ attnB,
             unsigned short* __restrict__ Yt)
{
    __shared__ unsigned char tile[128][200];
    const int tb = blockIdx.x;          // t*32 + b
    const int b  = tb & 31, tt = tb >> 5;
    const int c0 = blockIdx.y * 128;
    const int t  = threadIdx.x;
    for (int idx = t; idx < 128 * S_DIM; idx += 256) {
        const int cc = idx / S_DIM, s = idx - cc * S_DIM;
        const int c = c0 + cc;
        const int kbit = (spk[b * CS_ + c * S_DIM + s] >> (4 + tt)) & 1;
        const int abit = (attnB[(b * 8 + c / 48) * S_DIM + s] >> tt) & 1;
        tile[cc][s] = (unsigned char)(kbit & abit);
    }
    __syncthreads();
    for (int idx = t; idx < 128 * S_DIM; idx += 256) {
        const int s = idx >> 7, cc = idx & 127;
        Yt[(size_t)(tb * S_DIM + s) * C_DIM + c0 + cc] = tile[cc][s] ? 0x3C00 : 0;
    }
}

// ---------------------------------------------------------------------------
// Final: bias, BN, LIF over t -> spikes to d_out.
// ---------------------------------------------------------------------------
__global__ __launch_bounds__(256)
void bn_lif_out(const float* __restrict__ P, const float* __restrict__ bias,
                const float* __restrict__ gamma, const float* __restrict__ beta,
                const float* __restrict__ mean,  const float* __restrict__ var,
                float* __restrict__ out)
{
    const int i = blockIdx.x * 256 + threadIdx.x;   // over B*C*S
    if (i >= BCS) return;
    const int o = (i % CS_) / S_DIM;
    const float inv = gamma[o] / sqrtf(var[o] + 1e-5f);
    const float sh  = beta[o] - mean[o] * inv;
    const float bv  = bias[o];

    float v = 0.0f;
    #pragma unroll
    for (int t = 0; t < 4; ++t) {
        const float z = (P[t * BCS + i] + bv) * inv + sh;
        const float h = v + (z - v) * 0.5f;
        const int sp = (h >= 1.0f);
        v = sp ? 0.0f : h;
        out[t * BCS + i] = sp ? 1.0f : 0.0f;
    }
}

// ---------------------------------------------------------------------------
extern "C" void kernel_launch(void* const* d_in, const int* in_sizes, int n_in,
                              void* d_out, int out_size, void* d_ws, size_t ws_size,
                              hipStream_t stream)
{
    const float* x          = (const float*)d_in[0];
    const float* q_w        = (const float*)d_in[1];
    const float* q_gamma    = (const float*)d_in[2];
    const float* q_beta     = (const float*)d_in[3];
    const float* q_mean     = (const float*)d_in[4];
    const float* q_var      = (const float*)d_in[5];
    const float* k_w        = (const float*)d_in[6];
    const float* k_gamma    = (const float*)d_in[7];
    const float* k_beta     = (const float*)d_in[8];
    const float* k_mean     = (const float*)d_in[9];
    const float* k_var      = (const float*)d_in[10];
    const float* proj_w     = (const float*)d_in[11];
    const float* proj_b     = (const float*)d_in[12];
    const float* proj_gamma = (const float*)d_in[13];
    const float* proj_beta  = (const float*)d_in[14];
    const float* proj_mean  = (const float*)d_in[15];
    const float* proj_var   = (const float*)d_in[16];
    float* out = (float*)d_out;

    // workspace layout:
    float*    f0 = (float*)d_ws;            // Yq; later proj raw output P
    float*    f1 = f0 + NELEM;              // Yk
    _Float16* h0 = (_Float16*)(f1 + NELEM); // X0; later Yt (binary fp16)
    _Float16* h1 = h0 + NELEM;              // X1; later spk+attnB region
    _Float16* Wq0 = h1 + NELEM;             // 768x384
    _Float16* Wq1 = Wq0 + 768 * C_DIM;
    _Float16* Wp0 = Wq1 + 768 * C_DIM;      // 384x384
    _Float16* Wp1 = Wp0 + C_DIM * C_DIM;
    float2*   invsh = (float2*)(Wp1 + C_DIM * C_DIM);   // 768 entries
    unsigned char* spk   = (unsigned char*)h1;          // BCS bytes
    unsigned char* attnB = spk + BCS;                   // 50176 bytes

    split_w<<<1728, 256, 0, stream>>>(q_w, k_w, proj_w,
                                      q_gamma, q_beta, q_mean, q_var,
                                      k_gamma, k_beta, k_mean, k_var,
                                      Wq0, Wq1, Wp0, Wp1, invsh);
    split_x<<<dim3(128, 12), 256, 0, stream>>>(x, h0, h1);

    qk_mfma<<<dim3(196, 6), 256, 0, stream>>>(Wq0, Wq1, h0, h1, invsh, f0, f1);

    lif_spike_pack<<<(BCS + 255) / 256, 256, 0, stream>>>(f0, f1, spk);
    attn_compute<<<256, 256, 0, stream>>>(spk, attnB);
    build_y<<<dim3(128, 3), 256, 0, stream>>>(spk, attnB, (unsigned short*)h0);

    proj_mfma<<<dim3(196, 3), 256, 0, stream>>>(Wp0, Wp1, h0, f0);

    bn_lif_out<<<(BCS + 255) / 256, 256, 0, stream>>>(f0, proj_b,
                                                      proj_gamma, proj_beta,
                                                      proj_mean, proj_var, out);
}